// Round 1
// baseline (1308.179 us; speedup 1.0000x reference)
//
#include <hip/hip_runtime.h>

typedef unsigned long long u64;
typedef unsigned int u32;

#define NBOX 8192
#define NWORDS 128  // NBOX/64

// ---- monotone float<->uint mapping (order-preserving for all floats) ----
__device__ __forceinline__ u32 f32_mono(float f) {
  u32 u = __float_as_uint(f);
  return (u & 0x80000000u) ? ~u : (u | 0x80000000u);
}
__device__ __forceinline__ float mono_f32(u32 u) {
  u32 b = (u & 0x80000000u) ? (u ^ 0x80000000u) : ~u;
  return __uint_as_float(b);
}

// ---- K1: decode boxes, write to d_out, global max of all coords ----
__global__ void boxes_max_kernel(const float4* __restrict__ deltas,
                                 const float2* __restrict__ locs,
                                 const int* __restrict__ stride_p,
                                 float4* __restrict__ boxes_out,
                                 u32* __restrict__ gmax) {
  int i = blockIdx.x * blockDim.x + threadIdx.x;
  float s = (float)(*stride_p);
  float4 d = deltas[i];
  d.x = fmaxf(d.x, 0.f); d.y = fmaxf(d.y, 0.f);
  d.z = fmaxf(d.z, 0.f); d.w = fmaxf(d.w, 0.f);
  float2 c = locs[i];
  float4 b;
  b.x = c.x - s * d.x;
  b.y = c.y - s * d.y;
  b.z = c.x + s * d.z;
  b.w = c.y + s * d.w;
  boxes_out[i] = b;
  float m = fmaxf(fmaxf(b.x, b.y), fmaxf(b.z, b.w));
  u32 u = f32_mono(m);
#pragma unroll
  for (int off = 32; off > 0; off >>= 1) {
    u32 o = __shfl_xor(u, off);
    u = (u > o) ? u : o;
  }
  if ((threadIdx.x & 63) == 0) atomicMax(gmax, u);
}

// ---- K2: single-block bitonic sort of (~mono(score), idx) keys ----
// Ascending sort of key64 == stable descending argsort of scores.
__global__ __launch_bounds__(1024) void sort_kernel(const float* __restrict__ scores,
                                                    u64* __restrict__ keys, int n) {
  __shared__ u64 sm[NBOX];
  int t = threadIdx.x;
  for (int p = t; p < n; p += 1024) {
    u32 u = f32_mono(scores[p]);
    u32 inv = ~u;  // descending score
    sm[p] = ((u64)inv << 32) | (u32)p;
  }
  __syncthreads();
  for (int k = 2; k <= n; k <<= 1) {
    for (int j = k >> 1; j > 0; j >>= 1) {
      for (int p = t; p < n; p += 1024) {
        int ixj = p ^ j;
        if (ixj > p) {
          bool up = ((p & k) == 0);
          u64 a = sm[p], b = sm[ixj];
          if ((a > b) == up) { sm[p] = b; sm[ixj] = a; }
        }
      }
      __syncthreads();
    }
  }
  for (int p = t; p < n; p += 1024) keys[p] = sm[p];
}

// ---- K3: gather sorted boxes + class offsets; emit order output ----
__global__ void prep_kernel(const u64* __restrict__ keys,
                            const float4* __restrict__ boxes,
                            const int* __restrict__ class_ids,
                            const u32* __restrict__ gmax,
                            float4* __restrict__ bnms,
                            float* __restrict__ order_out, int n) {
  int i = blockIdx.x * blockDim.x + threadIdx.x;
  if (i >= n) return;
  u64 k = keys[i];
  int idx = (int)(u32)k;
  float maxc = mono_f32(*gmax);
  float off = (float)class_ids[idx] * (maxc + 1.0f);
  float4 b = boxes[idx];
  b.x += off; b.y += off; b.z += off; b.w += off;
  bnms[i] = b;
  order_out[i] = (float)idx;
}

// ---- K4: suppression bitmask. One block per row i; wave-ballot per 64-j word.
__global__ __launch_bounds__(256) void mask_kernel(const float4* __restrict__ bnms,
                                                   u64* __restrict__ mask, int n) {
  int i = blockIdx.x;
  float4 bi = bnms[i];
  float area_i = (bi.z - bi.x) * (bi.w - bi.y);
  int lane = threadIdx.x & 63;
  int wid = threadIdx.x >> 6;
  for (int w = wid; w < NWORDS; w += 4) {
    int j = w * 64 + lane;
    float4 bj = bnms[j];
    float ltx = fmaxf(bi.x, bj.x), lty = fmaxf(bi.y, bj.y);
    float rbx = fminf(bi.z, bj.z), rby = fminf(bi.w, bj.w);
    float ww = fmaxf(rbx - ltx, 0.f), hh = fmaxf(rby - lty, 0.f);
    float inter = ww * hh;
    float area_j = (bj.z - bj.x) * (bj.w - bj.y);
    float iou = inter / (area_i + area_j - inter);  // NaN (0/0) compares false, same as ref
    u64 m = __ballot((iou > 0.5f) && (j > i));
    if (lane == 0) mask[(size_t)i * NWORDS + w] = m;
  }
}

// ---- K5: serial greedy scan, single wave, barrier-free.
// Lane l owns remv words l (r0) and l+64 (r1). Speculative 8-row double-buffered
// prefetch of mask rows. Keep bit broadcast via one 32-bit shfl.
// Garbage in lower-triangle mask bits is harmless: bit j of remv is only ever
// read at iteration j, before any row i>j can OR into it... (rows i<j OR valid
// j>i bits; rows i>=j never affect the already-consumed bit).
__global__ void scan_kernel(const u64* __restrict__ mask,
                            const u64* __restrict__ keys,
                            float* __restrict__ keep_out, int n) {
  int lane = threadIdx.x;  // 0..63
  u64 r0 = 0, r1 = 0;
  u64 cA[8], cB[8], nA[8], nB[8];
#pragma unroll
  for (int r = 0; r < 8; r++) {
    cA[r] = mask[(size_t)r * NWORDS + lane];
    cB[r] = mask[(size_t)r * NWORDS + 64 + lane];
  }
  u64 mykey = keys[lane];  // superblock 0: rows 0..63
  int ngroups = n / 8;     // 1024
  for (int g = 0; g < ngroups; g++) {
    if (g + 1 < ngroups) {
#pragma unroll
      for (int r = 0; r < 8; r++) {
        size_t row = (size_t)(g + 1) * 8 + r;
        nA[r] = mask[row * NWORDS + lane];
        nB[r] = mask[row * NWORDS + 64 + lane];
      }
    }
#pragma unroll
    for (int r = 0; r < 8; r++) {
      int i = g * 8 + r;
      int w = i >> 6, bit = i & 63, owner = w & 63;
      int mybit = (int)((((w < 64) ? r0 : r1) >> bit) & 1ull);
      bool kept = (__shfl(mybit, owner) == 0);
      if (kept) { r0 |= cA[r]; r1 |= cB[r]; }
      if (lane == bit) keep_out[(u32)mykey] = kept ? 1.0f : 0.0f;
    }
    if (((g + 1) & 7) == 0 && (g + 1) < ngroups)
      mykey = keys[(size_t)(g + 1) * 8 + lane];
    if (g + 1 < ngroups) {
#pragma unroll
      for (int r = 0; r < 8; r++) { cA[r] = nA[r]; cB[r] = nB[r]; }
    }
  }
}

extern "C" void kernel_launch(void* const* d_in, const int* in_sizes, int n_in,
                              void* d_out, int out_size, void* d_ws, size_t ws_size,
                              hipStream_t stream) {
  const float* deltas = (const float*)d_in[0];
  const float* locs = (const float*)d_in[1];
  const float* scores = (const float*)d_in[2];
  const int* class_ids = (const int*)d_in[3];
  const int* stride_p = (const int*)d_in[4];
  int n = in_sizes[2];  // 8192

  float* boxes_out = (float*)d_out;            // n*4 floats
  float* keep_out = (float*)d_out + (size_t)n * 4;  // n floats (0/1)
  float* order_out = (float*)d_out + (size_t)n * 5; // n floats (indices)

  // workspace layout
  u32* gmax = (u32*)d_ws;                                        // 4 B
  u64* keys = (u64*)((char*)d_ws + 256);                          // 64 KiB
  float4* bnms = (float4*)((char*)d_ws + 256 + 65536);            // 128 KiB
  u64* mask = (u64*)((char*)d_ws + 256 + 65536 + 131072);         // 8 MiB

  hipMemsetAsync(d_ws, 0, 4, stream);  // reset gmax (capturable)

  boxes_max_kernel<<<n / 256, 256, 0, stream>>>(
      (const float4*)deltas, (const float2*)locs, stride_p,
      (float4*)boxes_out, gmax);

  sort_kernel<<<1, 1024, 0, stream>>>(scores, keys, n);

  prep_kernel<<<n / 256, 256, 0, stream>>>(
      keys, (const float4*)boxes_out, class_ids, gmax, bnms, order_out, n);

  mask_kernel<<<n, 256, 0, stream>>>(bnms, mask, n);

  scan_kernel<<<1, 64, 0, stream>>>(mask, keys, keep_out, n);
}

// Round 2
// 604.971 us; speedup vs baseline: 2.1624x; 2.1624x over previous
//
#include <hip/hip_runtime.h>

typedef unsigned long long u64;
typedef unsigned int u32;

#define NBOX 8192
#define NW64 128  // u64 words per mask row

// ---- monotone float<->uint mapping (order-preserving for all floats) ----
__device__ __forceinline__ u32 f32_mono(float f) {
  u32 u = __float_as_uint(f);
  return (u & 0x80000000u) ? ~u : (u | 0x80000000u);
}
__device__ __forceinline__ float mono_f32(u32 u) {
  u32 b = (u & 0x80000000u) ? (u ^ 0x80000000u) : ~u;
  return __uint_as_float(b);
}

__device__ __forceinline__ u64 readlane64(u64 v, int l) {
  u32 lo = __builtin_amdgcn_readlane((u32)v, l);
  u32 hi = __builtin_amdgcn_readlane((u32)(v >> 32), l);
  return ((u64)hi << 32) | (u64)lo;
}

// ---- K1: decode boxes, write to d_out, global max of all coords ----
__global__ void boxes_max_kernel(const float4* __restrict__ deltas,
                                 const float2* __restrict__ locs,
                                 const int* __restrict__ stride_p,
                                 float4* __restrict__ boxes_out,
                                 u32* __restrict__ gmax) {
  int i = blockIdx.x * blockDim.x + threadIdx.x;
  float s = (float)(*stride_p);
  float4 d = deltas[i];
  d.x = fmaxf(d.x, 0.f); d.y = fmaxf(d.y, 0.f);
  d.z = fmaxf(d.z, 0.f); d.w = fmaxf(d.w, 0.f);
  float2 c = locs[i];
  float4 b;
  b.x = c.x - s * d.x;
  b.y = c.y - s * d.y;
  b.z = c.x + s * d.z;
  b.w = c.y + s * d.w;
  boxes_out[i] = b;
  float m = fmaxf(fmaxf(b.x, b.y), fmaxf(b.z, b.w));
  u32 u = f32_mono(m);
#pragma unroll
  for (int off = 32; off > 0; off >>= 1) {
    u32 o = __shfl_xor(u, off);
    u = (u > o) ? u : o;
  }
  if ((threadIdx.x & 63) == 0) atomicMax(gmax, u);
}

// ---- K2: single-block bitonic sort of (~mono(score), idx) keys ----
__global__ __launch_bounds__(1024) void sort_kernel(const float* __restrict__ scores,
                                                    u64* __restrict__ keys, int n) {
  __shared__ u64 sm[NBOX];
  int t = threadIdx.x;
  for (int p = t; p < n; p += 1024) {
    u32 u = f32_mono(scores[p]);
    u32 inv = ~u;  // descending score
    sm[p] = ((u64)inv << 32) | (u32)p;
  }
  __syncthreads();
  for (int k = 2; k <= n; k <<= 1) {
    for (int j = k >> 1; j > 0; j >>= 1) {
      for (int p = t; p < n; p += 1024) {
        int ixj = p ^ j;
        if (ixj > p) {
          bool up = ((p & k) == 0);
          u64 a = sm[p], b = sm[ixj];
          if ((a > b) == up) { sm[p] = b; sm[ixj] = a; }
        }
      }
      __syncthreads();
    }
  }
  for (int p = t; p < n; p += 1024) keys[p] = sm[p];
}

// ---- K3: gather sorted boxes + class offsets; emit order output ----
__global__ void prep_kernel(const u64* __restrict__ keys,
                            const float4* __restrict__ boxes,
                            const int* __restrict__ class_ids,
                            const u32* __restrict__ gmax,
                            float4* __restrict__ bnms,
                            float* __restrict__ order_out, int n) {
  int i = blockIdx.x * blockDim.x + threadIdx.x;
  if (i >= n) return;
  u64 k = keys[i];
  int idx = (int)(u32)k;
  float maxc = mono_f32(*gmax);
  float off = (float)class_ids[idx] * (maxc + 1.0f);
  float4 b = boxes[idx];
  b.x += off; b.y += off; b.z += off; b.w += off;
  bnms[i] = b;
  order_out[i] = (float)idx;
}

// ---- K4: suppression bitmask. One block per row i; wave-ballot per 64-j word.
__global__ __launch_bounds__(256) void mask_kernel(const float4* __restrict__ bnms,
                                                   u64* __restrict__ mask, int n) {
  int i = blockIdx.x;
  float4 bi = bnms[i];
  float area_i = (bi.z - bi.x) * (bi.w - bi.y);
  int lane = threadIdx.x & 63;
  int wid = threadIdx.x >> 6;
  for (int w = wid; w < NW64; w += 4) {
    int j = w * 64 + lane;
    float4 bj = bnms[j];
    float ltx = fmaxf(bi.x, bj.x), lty = fmaxf(bi.y, bj.y);
    float rbx = fminf(bi.z, bj.z), rby = fminf(bi.w, bj.w);
    float ww = fmaxf(rbx - ltx, 0.f), hh = fmaxf(rby - lty, 0.f);
    float inter = ww * hh;
    float area_j = (bj.z - bj.x) * (bj.w - bj.y);
    float iou = inter / (area_i + area_j - inter);  // NaN (0/0) compares false, same as ref
    u64 m = __ballot((iou > 0.5f) && (j > i));
    if (lane == 0) mask[(size_t)i * NW64 + w] = m;
  }
}

// ---- K5: serial greedy scan, single wave.
// remv distributed: lane l owns u64 words 2l and 2l+1 (r0, r1).
// Per 64-row block b:
//   phase A (scalar chain): w = remv word b (readlane). Per row r:
//     d = readlane64(dg, r)  [dg = per-lane diagonal word mask[b*64+lane][b]]
//     sm = kept ? ~0 : 0  (pure SALU);  w |= d & sm;  K |= sm & (1<<r)
//   phase B (throughput): r0 |= row & sm, r1 |= row & sm — off the critical chain.
// Rows streamed 16 at a time through ping-pong register buffers X/Y
// (ulonglong2 = global_load_dwordx4 per row per lane).
// Lower-triangle garbage bits in mask rows are harmless: bit j is consumed at
// iteration j strictly before any row i>=j can OR garbage into it.
__global__ __launch_bounds__(64) void scan_kernel(const u64* __restrict__ mask,
                                                  const u64* __restrict__ keys,
                                                  float* __restrict__ keep_out) {
  const int lane = threadIdx.x;  // 0..63
  u64 r0 = 0, r1 = 0;            // remv words 2*lane, 2*lane+1
  u64 X[32], Y[32];              // 16 rows x 2 u64 each

  // prologue: fill X with rows 0..15
#pragma unroll
  for (int r = 0; r < 16; ++r) {
    ulonglong2 v = *reinterpret_cast<const ulonglong2*>(mask + (size_t)r * NW64 + 2 * lane);
    X[2 * r] = v.x; X[2 * r + 1] = v.y;
  }
  u64 dg_cur = mask[(size_t)lane * NW64 + 0];  // diag words of block 0
  u64 key_cur = keys[lane];
  u64 dg_nxt = 0, key_nxt = 0;

#define FILL(BUF, FBASE)                                                              \
  if ((FBASE) < NBOX) {                                                               \
    _Pragma("unroll")                                                                 \
    for (int r = 0; r < 16; ++r) {                                                    \
      ulonglong2 v = *reinterpret_cast<const ulonglong2*>(                            \
          mask + (size_t)((FBASE) + r) * NW64 + 2 * lane);                            \
      BUF[2 * r] = v.x; BUF[2 * r + 1] = v.y;                                         \
    }                                                                                 \
  }

#define STEP(BUFC, BUFN, S)                                                           \
  {                                                                                   \
    FILL(BUFN, b * 64 + ((S) + 1) * 16)                                               \
    _Pragma("unroll")                                                                 \
    for (int e = 0; e < 16; ++e) {                                                    \
      const int rl = (S) * 16 + e; /* compile-time literal 0..63 */                   \
      u64 d = readlane64(dg_cur, rl);                                                 \
      u64 bit = (w >> rl) & 1ull;                                                     \
      u64 sm = bit - 1ull; /* kept -> ~0, suppressed -> 0 */                          \
      w |= d & sm;                                                                    \
      K |= sm & (1ull << rl);                                                         \
      r0 |= BUFC[2 * e] & sm;                                                         \
      r1 |= BUFC[2 * e + 1] & sm;                                                     \
    }                                                                                 \
  }

  for (int b = 0; b < 128; ++b) {
    if (b + 1 < 128) {  // prefetch next block's diag + keys (one block of slack)
      dg_nxt = mask[(size_t)((b + 1) * 64 + lane) * NW64 + (b + 1)];
      key_nxt = keys[(size_t)(b + 1) * 64 + lane];
    }
    // w = current remv word b (uniform readlane from owning lane/register)
    u64 w = (b & 1) ? readlane64(r1, b >> 1) : readlane64(r0, b >> 1);
    u64 K = 0;

    STEP(X, Y, 0)
    STEP(Y, X, 1)
    STEP(X, Y, 2)
    STEP(Y, X, 3)

    // write keep bits for this block
    u64 kb = (K >> lane) & 1ull;
    keep_out[(u32)key_cur] = kb ? 1.0f : 0.0f;

    dg_cur = dg_nxt;
    key_cur = key_nxt;
  }
#undef STEP
#undef FILL
}

extern "C" void kernel_launch(void* const* d_in, const int* in_sizes, int n_in,
                              void* d_out, int out_size, void* d_ws, size_t ws_size,
                              hipStream_t stream) {
  const float* deltas = (const float*)d_in[0];
  const float* locs = (const float*)d_in[1];
  const float* scores = (const float*)d_in[2];
  const int* class_ids = (const int*)d_in[3];
  const int* stride_p = (const int*)d_in[4];
  int n = in_sizes[2];  // 8192

  float* boxes_out = (float*)d_out;                  // n*4 floats
  float* keep_out = (float*)d_out + (size_t)n * 4;   // n floats (0/1)
  float* order_out = (float*)d_out + (size_t)n * 5;  // n floats (indices)

  // workspace layout
  u32* gmax = (u32*)d_ws;                                 // 4 B
  u64* keys = (u64*)((char*)d_ws + 256);                  // 64 KiB
  float4* bnms = (float4*)((char*)d_ws + 256 + 65536);    // 128 KiB
  u64* mask = (u64*)((char*)d_ws + 256 + 65536 + 131072); // 8 MiB

  hipMemsetAsync(d_ws, 0, 4, stream);  // reset gmax (graph-capturable)

  boxes_max_kernel<<<n / 256, 256, 0, stream>>>(
      (const float4*)deltas, (const float2*)locs, stride_p,
      (float4*)boxes_out, gmax);

  sort_kernel<<<1, 1024, 0, stream>>>(scores, keys, n);

  prep_kernel<<<n / 256, 256, 0, stream>>>(
      keys, (const float4*)boxes_out, class_ids, gmax, bnms, order_out, n);

  mask_kernel<<<n, 256, 0, stream>>>(bnms, mask, n);

  scan_kernel<<<1, 64, 0, stream>>>(mask, keys, keep_out);
}

// Round 3
// 207.052 us; speedup vs baseline: 6.3181x; 2.9218x over previous
//
#include <hip/hip_runtime.h>

typedef unsigned long long u64;
typedef unsigned int u32;

#define NBOX 8192
#define NW64 128   // u64 words per mask row (fallback path)
#define NCLASS 80
#define MAXC 512   // per-class capacity (mean ~102, overflow impossible for this data)
#define CHKCAP 256

// ---- monotone float<->uint mapping (order-preserving for all floats) ----
__device__ __forceinline__ u32 f32_mono(float f) {
  u32 u = __float_as_uint(f);
  return (u & 0x80000000u) ? ~u : (u | 0x80000000u);
}
__device__ __forceinline__ float mono_f32(u32 u) {
  u32 b = (u & 0x80000000u) ? (u ^ 0x80000000u) : ~u;
  return __uint_as_float(b);
}
__device__ __forceinline__ u64 readlane64(u64 v, int l) {
  u32 lo = __builtin_amdgcn_readlane((u32)v, l);
  u32 hi = __builtin_amdgcn_readlane((u32)(v >> 32), l);
  return ((u64)hi << 32) | (u64)lo;
}

// ---- K1: decode boxes, write to d_out, global max of all coords ----
__global__ void boxes_max_kernel(const float4* __restrict__ deltas,
                                 const float2* __restrict__ locs,
                                 const int* __restrict__ stride_p,
                                 float4* __restrict__ boxes_out,
                                 u32* __restrict__ gmax) {
  int i = blockIdx.x * blockDim.x + threadIdx.x;
  float s = (float)(*stride_p);
  float4 d = deltas[i];
  d.x = fmaxf(d.x, 0.f); d.y = fmaxf(d.y, 0.f);
  d.z = fmaxf(d.z, 0.f); d.w = fmaxf(d.w, 0.f);
  float2 c = locs[i];
  float4 b;
  b.x = c.x - s * d.x;
  b.y = c.y - s * d.y;
  b.z = c.x + s * d.z;
  b.w = c.y + s * d.w;
  boxes_out[i] = b;
  float m = fmaxf(fmaxf(b.x, b.y), fmaxf(b.z, b.w));
  u32 u = f32_mono(m);
#pragma unroll
  for (int off = 32; off > 0; off >>= 1) {
    u32 o = __shfl_xor(u, off);
    u = (u > o) ? u : o;
  }
  if ((threadIdx.x & 63) == 0) atomicMax(gmax, u);
}

// ---- K2: single-block bitonic sort of (~mono(score), idx) keys ----
__global__ __launch_bounds__(1024) void sort_kernel(const float* __restrict__ scores,
                                                    u64* __restrict__ keys, int n) {
  __shared__ u64 sm[NBOX];
  int t = threadIdx.x;
  for (int p = t; p < n; p += 1024) {
    u32 u = f32_mono(scores[p]);
    u32 inv = ~u;  // descending score
    sm[p] = ((u64)inv << 32) | (u32)p;
  }
  __syncthreads();
  for (int k = 2; k <= n; k <<= 1) {
    for (int j = k >> 1; j > 0; j >>= 1) {
      for (int p = t; p < n; p += 1024) {
        int ixj = p ^ j;
        if (ixj > p) {
          bool up = ((p & k) == 0);
          u64 a = sm[p], b = sm[ixj];
          if ((a > b) == up) { sm[p] = b; sm[ixj] = a; }
        }
      }
      __syncthreads();
    }
  }
  for (int p = t; p < n; p += 1024) keys[p] = sm[p];
}

// ---- K3: gather sorted boxes + class offsets; emit order + sorted classes ----
__global__ void prep_kernel(const u64* __restrict__ keys,
                            const float4* __restrict__ boxes,
                            const int* __restrict__ class_ids,
                            const u32* __restrict__ gmax,
                            float4* __restrict__ bnms,
                            int* __restrict__ cls_sorted,
                            float* __restrict__ order_out, int n) {
  int i = blockIdx.x * blockDim.x + threadIdx.x;
  if (i >= n) return;
  u64 k = keys[i];
  int idx = (int)(u32)k;
  float maxc = mono_f32(*gmax);
  int cls = class_ids[idx];
  float off = (float)cls * (maxc + 1.0f);
  float4 b = boxes[idx];
  b.x += off; b.y += off; b.z += off; b.w += off;
  bnms[i] = b;
  cls_sorted[i] = cls;
  order_out[i] = (float)idx;
}

// ---- K4: cross-class hazard check. Adjacent-class offset boxes can only
// overlap if one box is in the extreme top-right margin (x2,y2 > M-65; since
// x1,y1 >= -64 by construction, the true bound is M+1-64, minus 2.0 fp slack)
// and the other in the extreme bottom-left margin (x1,y1 < 1). Test all such
// candidate pairs at a conservative IoU > 0.4 (reference threshold 0.5).
__global__ __launch_bounds__(256) void check_kernel(const float4* __restrict__ boxes,
                                                    const int* __restrict__ class_ids,
                                                    const u32* __restrict__ gmax,
                                                    int* __restrict__ flag, int n) {
  __shared__ float4 bxA[CHKCAP], bxB[CHKCAP];
  __shared__ int clsA[CHKCAP], clsB[CHKCAP];
  __shared__ int na, nb;
  int t = threadIdx.x;
  if (t == 0) { na = 0; nb = 0; }
  __syncthreads();
  float M = mono_f32(*gmax);
  float thrA = M - 65.0f;
  for (int base = 0; base < n; base += 256) {
    int i = base + t;
    float4 b = boxes[i];
    int cls = class_ids[i];
    if (b.z > thrA && b.w > thrA) {
      int p = atomicAdd(&na, 1);
      if (p < CHKCAP) { bxA[p] = b; clsA[p] = cls; }
    }
    if (b.x < 1.0f && b.y < 1.0f) {
      int p = atomicAdd(&nb, 1);
      if (p < CHKCAP) { bxB[p] = b; clsB[p] = cls; }
    }
  }
  __syncthreads();
  int NA = na < CHKCAP ? na : CHKCAP;
  int NB = nb < CHKCAP ? nb : CHKCAP;
  if (t == 0 && (na > CHKCAP || nb > CHKCAP)) atomicOr(flag, 1);  // conservative
  bool hit = false;
  for (int pr = t; pr < NA * NB; pr += 256) {
    int a = pr / NB, b = pr % NB;
    if (clsB[b] != clsA[a] + 1) continue;  // only adjacent bands can touch
    float offa = (float)clsA[a] * (M + 1.0f);
    float offb = (float)clsB[b] * (M + 1.0f);
    float4 A = bxA[a], B = bxB[b];
    A.x += offa; A.y += offa; A.z += offa; A.w += offa;
    B.x += offb; B.y += offb; B.z += offb; B.w += offb;
    float ltx = fmaxf(A.x, B.x), lty = fmaxf(A.y, B.y);
    float rbx = fminf(A.z, B.z), rby = fminf(A.w, B.w);
    float ww = fmaxf(rbx - ltx, 0.f), hh = fmaxf(rby - lty, 0.f);
    float inter = ww * hh;
    float aa = (A.z - A.x) * (A.w - A.y);
    float ab = (B.z - B.x) * (B.w - B.y);
    float iou = inter / (aa + ab - inter);
    if (iou > 0.4f) hit = true;
  }
  if (hit) atomicOr(flag, 1);
}

// ---- K5: per-class independent greedy NMS (valid when flag==0).
// One block per class. Phase 1: ordered ballot-compaction of this class's
// sorted positions. Phase 2: wave-0 greedy NMS over <=MAXC boxes in LDS
// (bit-identical IoU arithmetic to the reference's offset-box formula).
__global__ __launch_bounds__(256) void class_nms_kernel(
    const u64* __restrict__ keys, const int* __restrict__ cls_sorted,
    const float4* __restrict__ bnms, float* __restrict__ keep_out, int n) {
  int c = blockIdx.x;
  int t = threadIdx.x;
  int lane = t & 63, wid = t >> 6;
  __shared__ unsigned short list[MAXC];
  __shared__ float4 bx[MAXC];
  __shared__ int wcnt[4];
  __shared__ int cnt;
  __shared__ u64 supp[MAXC / 64];
  if (t == 0) cnt = 0;
  __syncthreads();
  for (int base = 0; base < n; base += 256) {
    int pos = base + t;
    bool pred = (cls_sorted[pos] == c);
    u64 bal = __ballot(pred);
    if (lane == 0) wcnt[wid] = __popcll(bal);
    __syncthreads();
    int off = cnt;
    for (int w = 0; w < wid; ++w) off += wcnt[w];
    if (pred) {
      int r = __popcll(bal & ((1ull << lane) - 1ull));
      int p = off + r;
      if (p < MAXC) list[p] = (unsigned short)pos;
    }
    __syncthreads();
    if (t == 0) cnt += wcnt[0] + wcnt[1] + wcnt[2] + wcnt[3];
    __syncthreads();
  }
  int nc = cnt < MAXC ? cnt : MAXC;
  for (int k = t; k < nc; k += 256) bx[k] = bnms[list[k]];
  if (t < MAXC / 64) supp[t] = 0;
  __syncthreads();
  if (wid == 0) {
    for (int i = 0; i < nc; ++i) {
      if ((supp[i >> 6] >> (i & 63)) & 1ull) continue;
      float4 bi = bx[i];
      float area_i = (bi.z - bi.x) * (bi.w - bi.y);
      for (int jb = i + 1; jb < nc; jb += 64) {
        int j = jb + lane;
        bool p = false;
        if (j < nc) {
          float4 bj = bx[j];
          float ltx = fmaxf(bi.x, bj.x), lty = fmaxf(bi.y, bj.y);
          float rbx = fminf(bi.z, bj.z), rby = fminf(bi.w, bj.w);
          float ww = fmaxf(rbx - ltx, 0.f), hh = fmaxf(rby - lty, 0.f);
          float inter = ww * hh;
          float area_j = (bj.z - bj.x) * (bj.w - bj.y);
          float iou = inter / (area_i + area_j - inter);
          p = iou > 0.5f;
        }
        u64 m = __ballot(p);
        if (lane == 0 && m) {
          int w0 = jb >> 6, sh = jb & 63;
          supp[w0] |= (m << sh);
          if (sh && (w0 + 1) < MAXC / 64) supp[w0 + 1] |= (m >> (64 - sh));
        }
      }
    }
  }
  __syncthreads();
  for (int k = t; k < nc; k += 256) {
    int pos = list[k];
    u32 oidx = (u32)keys[pos];
    keep_out[oidx] = ((supp[k >> 6] >> (k & 63)) & 1ull) ? 0.0f : 1.0f;
  }
}

// ---- Fallback path (exact, runs only when flag != 0) ----
__global__ __launch_bounds__(256) void mask_kernel(const float4* __restrict__ bnms,
                                                   u64* __restrict__ mask,
                                                   const int* __restrict__ flag, int n) {
  if (*flag == 0) return;
  int i = blockIdx.x;
  float4 bi = bnms[i];
  float area_i = (bi.z - bi.x) * (bi.w - bi.y);
  int lane = threadIdx.x & 63;
  int wid = threadIdx.x >> 6;
  for (int w = wid; w < NW64; w += 4) {
    int j = w * 64 + lane;
    float4 bj = bnms[j];
    float ltx = fmaxf(bi.x, bj.x), lty = fmaxf(bi.y, bj.y);
    float rbx = fminf(bi.z, bj.z), rby = fminf(bi.w, bj.w);
    float ww = fmaxf(rbx - ltx, 0.f), hh = fmaxf(rby - lty, 0.f);
    float inter = ww * hh;
    float area_j = (bj.z - bj.x) * (bj.w - bj.y);
    float iou = inter / (area_i + area_j - inter);
    u64 m = __ballot((iou > 0.5f) && (j > i));
    if (lane == 0) mask[(size_t)i * NW64 + w] = m;
  }
}

__global__ __launch_bounds__(64) void scan_kernel(const u64* __restrict__ mask,
                                                  const u64* __restrict__ keys,
                                                  float* __restrict__ keep_out,
                                                  const int* __restrict__ flag) {
  if (*flag == 0) return;
  const int lane = threadIdx.x;
  u64 r0 = 0, r1 = 0;
  u64 X[32], Y[32];
#pragma unroll
  for (int r = 0; r < 16; ++r) {
    ulonglong2 v = *reinterpret_cast<const ulonglong2*>(mask + (size_t)r * NW64 + 2 * lane);
    X[2 * r] = v.x; X[2 * r + 1] = v.y;
  }
  u64 dg_cur = mask[(size_t)lane * NW64 + 0];
  u64 key_cur = keys[lane];
  u64 dg_nxt = 0, key_nxt = 0;

#define FILL(BUF, FBASE)                                                              \
  if ((FBASE) < NBOX) {                                                               \
    _Pragma("unroll")                                                                 \
    for (int r = 0; r < 16; ++r) {                                                    \
      ulonglong2 v = *reinterpret_cast<const ulonglong2*>(                            \
          mask + (size_t)((FBASE) + r) * NW64 + 2 * lane);                            \
      BUF[2 * r] = v.x; BUF[2 * r + 1] = v.y;                                         \
    }                                                                                 \
  }
#define STEP(BUFC, BUFN, S)                                                           \
  {                                                                                   \
    FILL(BUFN, b * 64 + ((S) + 1) * 16)                                               \
    _Pragma("unroll")                                                                 \
    for (int e = 0; e < 16; ++e) {                                                    \
      const int rl = (S) * 16 + e;                                                    \
      u64 d = readlane64(dg_cur, rl);                                                 \
      u64 bit = (w >> rl) & 1ull;                                                     \
      u64 sm = bit - 1ull;                                                            \
      w |= d & sm;                                                                    \
      K |= sm & (1ull << rl);                                                         \
      r0 |= BUFC[2 * e] & sm;                                                         \
      r1 |= BUFC[2 * e + 1] & sm;                                                     \
    }                                                                                 \
  }
  for (int b = 0; b < 128; ++b) {
    if (b + 1 < 128) {
      dg_nxt = mask[(size_t)((b + 1) * 64 + lane) * NW64 + (b + 1)];
      key_nxt = keys[(size_t)(b + 1) * 64 + lane];
    }
    u64 w = (b & 1) ? readlane64(r1, b >> 1) : readlane64(r0, b >> 1);
    u64 K = 0;
    STEP(X, Y, 0)
    STEP(Y, X, 1)
    STEP(X, Y, 2)
    STEP(Y, X, 3)
    u64 kb = (K >> lane) & 1ull;
    keep_out[(u32)key_cur] = kb ? 1.0f : 0.0f;
    dg_cur = dg_nxt;
    key_cur = key_nxt;
  }
#undef STEP
#undef FILL
}

extern "C" void kernel_launch(void* const* d_in, const int* in_sizes, int n_in,
                              void* d_out, int out_size, void* d_ws, size_t ws_size,
                              hipStream_t stream) {
  const float* deltas = (const float*)d_in[0];
  const float* locs = (const float*)d_in[1];
  const float* scores = (const float*)d_in[2];
  const int* class_ids = (const int*)d_in[3];
  const int* stride_p = (const int*)d_in[4];
  int n = in_sizes[2];  // 8192

  float* boxes_out = (float*)d_out;                  // n*4 floats
  float* keep_out = (float*)d_out + (size_t)n * 4;   // n floats (0/1)
  float* order_out = (float*)d_out + (size_t)n * 5;  // n floats (indices)

  // workspace layout (total footprint identical to proven round-2 usage)
  u32* gmax = (u32*)d_ws;                                   // @0, 4 B
  int* flag = (int*)((char*)d_ws + 4);                      // @4, 4 B
  u64* keys = (u64*)((char*)d_ws + 256);                    // 64 KiB
  float4* bnms = (float4*)((char*)d_ws + 256 + 65536);      // 128 KiB
  char* maskbase = (char*)d_ws + 256 + 65536 + 131072;      // 8 MiB region
  int* cls_sorted = (int*)maskbase;  // 32 KiB, lifetime disjoint from mask
  u64* mask = (u64*)maskbase;        // fallback only, written after cls use

  hipMemsetAsync(d_ws, 0, 16, stream);  // gmax + flag (graph-capturable)

  boxes_max_kernel<<<n / 256, 256, 0, stream>>>(
      (const float4*)deltas, (const float2*)locs, stride_p,
      (float4*)boxes_out, gmax);

  sort_kernel<<<1, 1024, 0, stream>>>(scores, keys, n);

  prep_kernel<<<n / 256, 256, 0, stream>>>(
      keys, (const float4*)boxes_out, class_ids, gmax, bnms, cls_sorted,
      order_out, n);

  check_kernel<<<1, 256, 0, stream>>>(
      (const float4*)boxes_out, class_ids, gmax, flag, n);

  class_nms_kernel<<<NCLASS, 256, 0, stream>>>(keys, cls_sorted, bnms, keep_out, n);

  mask_kernel<<<n, 256, 0, stream>>>(bnms, mask, flag, n);

  scan_kernel<<<1, 64, 0, stream>>>(mask, keys, keep_out, flag);
}

// Round 4
// 85.323 us; speedup vs baseline: 15.3322x; 2.4267x over previous
//
#include <hip/hip_runtime.h>

typedef unsigned long long u64;
typedef unsigned int u32;

#define NBOX 8192
#define NW64 128    // u64 words per mask row (fallback path)
#define NCLASS 80
#define MAXC 512    // per-class capacity (mean ~102; overflow -> exact fallback)
#define CHKCAP 256
#define NS 16       // rank slices
#define SLICE (NBOX / NS)  // 512

// ---- monotone float<->uint mapping (order-preserving for all floats) ----
__device__ __forceinline__ u32 f32_mono(float f) {
  u32 u = __float_as_uint(f);
  return (u & 0x80000000u) ? ~u : (u | 0x80000000u);
}
__device__ __forceinline__ float mono_f32(u32 u) {
  u32 b = (u & 0x80000000u) ? (u ^ 0x80000000u) : ~u;
  return __uint_as_float(b);
}
__device__ __forceinline__ u64 readlane64(u64 v, int l) {
  u32 lo = __builtin_amdgcn_readlane((u32)v, l);
  u32 hi = __builtin_amdgcn_readlane((u32)(v >> 32), l);
  return ((u64)hi << 32) | (u64)lo;
}

// ---- K1: fused rank-by-enumeration + box decode/global-max (slice 0).
// Rank key: (~mono(score) << 32) | (idx << 8) | cls.
// Ascending key == (score desc, idx asc) — cls in low 8 bits never affects
// ordering (idx unique, dominates) but gives free class-equality testing.
// Each block: 256 i's x one 512-wide j slice; counts per-(i,slice):
//   cnt  = #{j in slice : key_j < key_i}          (global rank partial)
//   ccnt = #{j in slice : key_j < key_i, cls==}   (class rank partial)
__global__ __launch_bounds__(256) void rank_decode_kernel(
    const float* __restrict__ scores, const int* __restrict__ class_ids,
    const float4* __restrict__ deltas, const float2* __restrict__ locs,
    const int* __restrict__ stride_p, float4* __restrict__ boxes_out,
    u32* __restrict__ gmax, int* __restrict__ rankp, int* __restrict__ rcp) {
  int t = threadIdx.x;
  int i = blockIdx.x * 256 + t;
  int slice = blockIdx.y;

  if (slice == 0) {  // decode boxes + global max (block-uniform branch)
    float s = (float)(*stride_p);
    float4 d = deltas[i];
    d.x = fmaxf(d.x, 0.f); d.y = fmaxf(d.y, 0.f);
    d.z = fmaxf(d.z, 0.f); d.w = fmaxf(d.w, 0.f);
    float2 c = locs[i];
    float4 b;
    b.x = c.x - s * d.x;
    b.y = c.y - s * d.y;
    b.z = c.x + s * d.z;
    b.w = c.y + s * d.w;
    boxes_out[i] = b;
    float m = fmaxf(fmaxf(b.x, b.y), fmaxf(b.z, b.w));
    u32 u = f32_mono(m);
#pragma unroll
    for (int off = 32; off > 0; off >>= 1) {
      u32 o = __shfl_xor(u, off);
      u = (u > o) ? u : o;
    }
    if ((t & 63) == 0) atomicMax(gmax, u);
  }

  __shared__ u64 kt[SLICE];
  for (int p = t; p < SLICE; p += 256) {
    int j = slice * SLICE + p;
    u32 mj = f32_mono(scores[j]);
    kt[p] = ((u64)(~mj) << 32) | ((u32)j << 8) | (u32)(class_ids[j] & 0xff);
  }
  __syncthreads();

  u32 mi = f32_mono(scores[i]);
  u32 ci = (u32)(class_ids[i] & 0xff);
  u64 ki = ((u64)(~mi) << 32) | ((u32)i << 8) | ci;
  int cnt = 0, ccnt = 0;
#pragma unroll 8
  for (int p = 0; p < SLICE; ++p) {
    u64 kj = kt[p];  // wave-uniform address -> LDS broadcast, no conflicts
    bool less = kj < ki;
    bool ceq = (((u32)(kj ^ ki)) & 0xffu) == 0u;
    cnt += less ? 1 : 0;
    ccnt += (less && ceq) ? 1 : 0;
  }
  rankp[slice * NBOX + i] = cnt;
  rcp[slice * NBOX + i] = ccnt;
}

// ---- K2: scatter by rank: sorted keys, offset boxes, order output, and
// per-class sorted lists (packed (idx<<16)|sorted_pos). All-in-one prep.
__global__ __launch_bounds__(256) void scatter_prep_kernel(
    const float* __restrict__ scores, const int* __restrict__ class_ids,
    const float4* __restrict__ boxes, const u32* __restrict__ gmax,
    const int* __restrict__ rankp, const int* __restrict__ rcp,
    u64* __restrict__ keys, float4* __restrict__ bnms,
    u32* __restrict__ clist, int* __restrict__ ccount,
    float* __restrict__ order_out, int* __restrict__ flag) {
  int i = blockIdx.x * 256 + threadIdx.x;
  int r = 0, rc = 0;
#pragma unroll
  for (int s = 0; s < NS; ++s) {  // coalesced within each slice row
    r += rankp[s * NBOX + i];
    rc += rcp[s * NBOX + i];
  }
  u32 mi = f32_mono(scores[i]);
  keys[r] = ((u64)(~mi) << 32) | (u32)i;  // clean key for fallback scan
  int cls = class_ids[i];
  float maxc = mono_f32(*gmax);
  float off = (float)cls * (maxc + 1.0f);
  float4 b = boxes[i];
  b.x += off; b.y += off; b.z += off; b.w += off;
  bnms[r] = b;
  order_out[r] = (float)i;
  if (rc < MAXC)
    clist[cls * MAXC + rc] = ((u32)i << 16) | (u32)r;
  else
    atomicOr(flag, 1);  // class overflow -> exact fallback
  atomicAdd(&ccount[cls], 1);
}

// ---- K3: per-class greedy NMS (blocks 0..79) + cross-class hazard check
// (block 80). Valid when flag stays 0; otherwise fallback overwrites.
__global__ __launch_bounds__(256) void class_nms_kernel(
    const u32* __restrict__ clist, const int* __restrict__ ccount,
    const float4* __restrict__ bnms, float* __restrict__ keep_out,
    const float4* __restrict__ boxes, const int* __restrict__ class_ids,
    const u32* __restrict__ gmax, int* __restrict__ flag, int n) {
  int t = threadIdx.x;

  if (blockIdx.x == NCLASS) {
    // Cross-class hazard check: adjacent-class offset boxes can only overlap
    // if one box hugs the top-right margin (x2,y2 > M-65; x1,y1 >= -64 by
    // construction) and the other the bottom-left margin (x1,y1 < 1).
    // Conservative IoU > 0.4 vs reference 0.5.
    __shared__ float4 bxA[CHKCAP], bxB[CHKCAP];
    __shared__ int clsA[CHKCAP], clsB[CHKCAP];
    __shared__ int na, nb;
    if (t == 0) { na = 0; nb = 0; }
    __syncthreads();
    float M = mono_f32(*gmax);
    float thrA = M - 65.0f;
    for (int base = 0; base < n; base += 256) {
      int i = base + t;
      float4 b = boxes[i];
      int cls = class_ids[i];
      if (b.z > thrA && b.w > thrA) {
        int p = atomicAdd(&na, 1);
        if (p < CHKCAP) { bxA[p] = b; clsA[p] = cls; }
      }
      if (b.x < 1.0f && b.y < 1.0f) {
        int p = atomicAdd(&nb, 1);
        if (p < CHKCAP) { bxB[p] = b; clsB[p] = cls; }
      }
    }
    __syncthreads();
    int NA = na < CHKCAP ? na : CHKCAP;
    int NB = nb < CHKCAP ? nb : CHKCAP;
    if (t == 0 && (na > CHKCAP || nb > CHKCAP)) atomicOr(flag, 1);
    bool hit = false;
    for (int pr = t; pr < NA * NB; pr += 256) {
      int a = pr / NB, b2 = pr % NB;
      if (clsB[b2] != clsA[a] + 1) continue;
      float offa = (float)clsA[a] * (M + 1.0f);
      float offb = (float)clsB[b2] * (M + 1.0f);
      float4 A = bxA[a], B = bxB[b2];
      A.x += offa; A.y += offa; A.z += offa; A.w += offa;
      B.x += offb; B.y += offb; B.z += offb; B.w += offb;
      float ltx = fmaxf(A.x, B.x), lty = fmaxf(A.y, B.y);
      float rbx = fminf(A.z, B.z), rby = fminf(A.w, B.w);
      float ww = fmaxf(rbx - ltx, 0.f), hh = fmaxf(rby - lty, 0.f);
      float inter = ww * hh;
      float aa = (A.z - A.x) * (A.w - A.y);
      float ab = (B.z - B.x) * (B.w - B.y);
      float iou = inter / (aa + ab - inter);
      if (iou > 0.4f) hit = true;
    }
    if (hit) atomicOr(flag, 1);
    return;
  }

  int c = blockIdx.x;
  __shared__ u32 list[MAXC];
  __shared__ float4 bx[MAXC];
  __shared__ u64 supp[MAXC / 64];
  int nc = ccount[c];
  nc = nc < MAXC ? nc : MAXC;
  for (int k = t; k < nc; k += 256) {
    u32 e = clist[c * MAXC + k];
    list[k] = e;
    bx[k] = bnms[e & 0xffffu];
  }
  if (t < MAXC / 64) supp[t] = 0;
  __syncthreads();
  if (t < 64) {  // wave 0: serial greedy over <=nc boxes
    int lane = t;
    for (int i = 0; i < nc; ++i) {
      if ((supp[i >> 6] >> (i & 63)) & 1ull) continue;
      float4 bi = bx[i];
      float area_i = (bi.z - bi.x) * (bi.w - bi.y);
      for (int jb = i + 1; jb < nc; jb += 64) {
        int j = jb + lane;
        bool p = false;
        if (j < nc) {
          float4 bj = bx[j];
          float ltx = fmaxf(bi.x, bj.x), lty = fmaxf(bi.y, bj.y);
          float rbx = fminf(bi.z, bj.z), rby = fminf(bi.w, bj.w);
          float ww = fmaxf(rbx - ltx, 0.f), hh = fmaxf(rby - lty, 0.f);
          float inter = ww * hh;
          float area_j = (bj.z - bj.x) * (bj.w - bj.y);
          float iou = inter / (area_i + area_j - inter);
          p = iou > 0.5f;
        }
        u64 m = __ballot(p);
        if (lane == 0 && m) {
          int w0 = jb >> 6, sh = jb & 63;
          supp[w0] |= (m << sh);
          if (sh && (w0 + 1) < MAXC / 64) supp[w0 + 1] |= (m >> (64 - sh));
        }
      }
    }
  }
  __syncthreads();
  for (int k = t; k < nc; k += 256)
    keep_out[list[k] >> 16] = ((supp[k >> 6] >> (k & 63)) & 1ull) ? 0.0f : 1.0f;
}

// ---- Exact fallback path (runs only when flag != 0) ----
__global__ __launch_bounds__(256) void mask_kernel(const float4* __restrict__ bnms,
                                                   u64* __restrict__ mask,
                                                   const int* __restrict__ flag, int n) {
  if (*flag == 0) return;
  int lane = threadIdx.x & 63;
  int wid = threadIdx.x >> 6;
  for (int rr = 0; rr < 8; ++rr) {
    int i = blockIdx.x * 8 + rr;
    float4 bi = bnms[i];
    float area_i = (bi.z - bi.x) * (bi.w - bi.y);
    for (int w = wid; w < NW64; w += 4) {
      int j = w * 64 + lane;
      float4 bj = bnms[j];
      float ltx = fmaxf(bi.x, bj.x), lty = fmaxf(bi.y, bj.y);
      float rbx = fminf(bi.z, bj.z), rby = fminf(bi.w, bj.w);
      float ww = fmaxf(rbx - ltx, 0.f), hh = fmaxf(rby - lty, 0.f);
      float inter = ww * hh;
      float area_j = (bj.z - bj.x) * (bj.w - bj.y);
      float iou = inter / (area_i + area_j - inter);
      u64 m = __ballot((iou > 0.5f) && (j > i));
      if (lane == 0) mask[(size_t)i * NW64 + w] = m;
    }
  }
}

__global__ __launch_bounds__(64) void scan_kernel(const u64* __restrict__ mask,
                                                  const u64* __restrict__ keys,
                                                  float* __restrict__ keep_out,
                                                  const int* __restrict__ flag) {
  if (*flag == 0) return;
  const int lane = threadIdx.x;
  u64 r0 = 0, r1 = 0;
  u64 X[32], Y[32];
#pragma unroll
  for (int r = 0; r < 16; ++r) {
    ulonglong2 v = *reinterpret_cast<const ulonglong2*>(mask + (size_t)r * NW64 + 2 * lane);
    X[2 * r] = v.x; X[2 * r + 1] = v.y;
  }
  u64 dg_cur = mask[(size_t)lane * NW64 + 0];
  u64 key_cur = keys[lane];
  u64 dg_nxt = 0, key_nxt = 0;

#define FILL(BUF, FBASE)                                                              \
  if ((FBASE) < NBOX) {                                                               \
    _Pragma("unroll")                                                                 \
    for (int r = 0; r < 16; ++r) {                                                    \
      ulonglong2 v = *reinterpret_cast<const ulonglong2*>(                            \
          mask + (size_t)((FBASE) + r) * NW64 + 2 * lane);                            \
      BUF[2 * r] = v.x; BUF[2 * r + 1] = v.y;                                         \
    }                                                                                 \
  }
#define STEP(BUFC, BUFN, S)                                                           \
  {                                                                                   \
    FILL(BUFN, b * 64 + ((S) + 1) * 16)                                               \
    _Pragma("unroll")                                                                 \
    for (int e = 0; e < 16; ++e) {                                                    \
      const int rl = (S) * 16 + e;                                                    \
      u64 d = readlane64(dg_cur, rl);                                                 \
      u64 bit = (w >> rl) & 1ull;                                                     \
      u64 sm = bit - 1ull;                                                            \
      w |= d & sm;                                                                    \
      K |= sm & (1ull << rl);                                                         \
      r0 |= BUFC[2 * e] & sm;                                                         \
      r1 |= BUFC[2 * e + 1] & sm;                                                     \
    }                                                                                 \
  }
  for (int b = 0; b < 128; ++b) {
    if (b + 1 < 128) {
      dg_nxt = mask[(size_t)((b + 1) * 64 + lane) * NW64 + (b + 1)];
      key_nxt = keys[(size_t)(b + 1) * 64 + lane];
    }
    u64 w = (b & 1) ? readlane64(r1, b >> 1) : readlane64(r0, b >> 1);
    u64 K = 0;
    STEP(X, Y, 0)
    STEP(Y, X, 1)
    STEP(X, Y, 2)
    STEP(Y, X, 3)
    u64 kb = (K >> lane) & 1ull;
    keep_out[(u32)key_cur] = kb ? 1.0f : 0.0f;
    dg_cur = dg_nxt;
    key_cur = key_nxt;
  }
#undef STEP
#undef FILL
}

extern "C" void kernel_launch(void* const* d_in, const int* in_sizes, int n_in,
                              void* d_out, int out_size, void* d_ws, size_t ws_size,
                              hipStream_t stream) {
  const float* deltas = (const float*)d_in[0];
  const float* locs = (const float*)d_in[1];
  const float* scores = (const float*)d_in[2];
  const int* class_ids = (const int*)d_in[3];
  const int* stride_p = (const int*)d_in[4];
  int n = in_sizes[2];  // 8192

  float* boxes_out = (float*)d_out;                  // n*4 floats
  float* keep_out = (float*)d_out + (size_t)n * 4;   // n floats (0/1)
  float* order_out = (float*)d_out + (size_t)n * 5;  // n floats (indices)

  // workspace layout
  u32* gmax = (u32*)d_ws;                        // @0
  int* flag = (int*)((char*)d_ws + 4);           // @4
  int* ccount = (int*)((char*)d_ws + 64);        // 80*4 B
  u64* keys = (u64*)((char*)d_ws + 4096);        // 64 KiB
  float4* bnms = (float4*)((char*)d_ws + 4096 + 65536);  // 128 KiB
  char* base2 = (char*)d_ws + 4096 + 65536 + 131072;
  int* rankp = (int*)base2;                       // NS*8192*4 = 512 KiB
  int* rcp = (int*)(base2 + 512 * 1024);          // 512 KiB
  u32* clist = (u32*)(base2 + 1024 * 1024);       // 80*512*4 = 160 KiB
  u64* mask = (u64*)base2;  // 8 MiB fallback overlay (lifetimes disjoint)

  hipMemsetAsync(d_ws, 0, 1024, stream);  // gmax + flag + ccount

  rank_decode_kernel<<<dim3(n / 256, NS), 256, 0, stream>>>(
      scores, class_ids, (const float4*)deltas, (const float2*)locs, stride_p,
      (float4*)boxes_out, gmax, rankp, rcp);

  scatter_prep_kernel<<<n / 256, 256, 0, stream>>>(
      scores, class_ids, (const float4*)boxes_out, gmax, rankp, rcp, keys,
      bnms, clist, ccount, order_out, flag);

  class_nms_kernel<<<NCLASS + 1, 256, 0, stream>>>(
      clist, ccount, bnms, keep_out, (const float4*)boxes_out, class_ids,
      gmax, flag, n);

  mask_kernel<<<n / 8, 256, 0, stream>>>(bnms, mask, flag, n);

  scan_kernel<<<1, 64, 0, stream>>>(mask, keys, keep_out, flag);
}

// Round 5
// 72.021 us; speedup vs baseline: 18.1638x; 1.1847x over previous
//
#include <hip/hip_runtime.h>

typedef unsigned long long u64;
typedef unsigned int u32;

#define NBOX 8192
#define NW64 128    // u64 words per mask row (fallback path)
#define NCLASS 80
#define MAXC 512    // clist capacity per class
#define NCMAX 256   // fast-path class size cap (nc>256 is ~9 sigma -> fallback)
#define CHKCAP 256
#define NS 16       // rank slices
#define SLICE (NBOX / NS)  // 512

// ---- monotone float<->uint mapping (order-preserving for all floats) ----
__device__ __forceinline__ u32 f32_mono(float f) {
  u32 u = __float_as_uint(f);
  return (u & 0x80000000u) ? ~u : (u | 0x80000000u);
}
__device__ __forceinline__ float mono_f32(u32 u) {
  u32 b = (u & 0x80000000u) ? (u ^ 0x80000000u) : ~u;
  return __uint_as_float(b);
}
__device__ __forceinline__ u64 readlane64(u64 v, int l) {
  u32 lo = __builtin_amdgcn_readlane((u32)v, l);
  u32 hi = __builtin_amdgcn_readlane((u32)(v >> 32), l);
  return ((u64)hi << 32) | (u64)lo;
}
__device__ __forceinline__ float readlane_f(float v, int l) {
  return __uint_as_float(__builtin_amdgcn_readlane(__float_as_uint(v), l));
}

// ---- K1: fused rank-by-enumeration + box decode/global-max (slice 0).
// Rank key: (~mono(score) << 32) | (idx << 8) | cls.
__global__ __launch_bounds__(256) void rank_decode_kernel(
    const float* __restrict__ scores, const int* __restrict__ class_ids,
    const float4* __restrict__ deltas, const float2* __restrict__ locs,
    const int* __restrict__ stride_p, float4* __restrict__ boxes_out,
    u32* __restrict__ gmax, int* __restrict__ rankp, int* __restrict__ rcp) {
  int t = threadIdx.x;
  int i = blockIdx.x * 256 + t;
  int slice = blockIdx.y;

  if (slice == 0) {  // decode boxes + global max (block-uniform branch)
    float s = (float)(*stride_p);
    float4 d = deltas[i];
    d.x = fmaxf(d.x, 0.f); d.y = fmaxf(d.y, 0.f);
    d.z = fmaxf(d.z, 0.f); d.w = fmaxf(d.w, 0.f);
    float2 c = locs[i];
    float4 b;
    b.x = c.x - s * d.x;
    b.y = c.y - s * d.y;
    b.z = c.x + s * d.z;
    b.w = c.y + s * d.w;
    boxes_out[i] = b;
    float m = fmaxf(fmaxf(b.x, b.y), fmaxf(b.z, b.w));
    u32 u = f32_mono(m);
#pragma unroll
    for (int off = 32; off > 0; off >>= 1) {
      u32 o = __shfl_xor(u, off);
      u = (u > o) ? u : o;
    }
    if ((t & 63) == 0) atomicMax(gmax, u);
  }

  __shared__ u64 kt[SLICE];
  for (int p = t; p < SLICE; p += 256) {
    int j = slice * SLICE + p;
    u32 mj = f32_mono(scores[j]);
    kt[p] = ((u64)(~mj) << 32) | ((u32)j << 8) | (u32)(class_ids[j] & 0xff);
  }
  __syncthreads();

  u32 mi = f32_mono(scores[i]);
  u32 ci = (u32)(class_ids[i] & 0xff);
  u64 ki = ((u64)(~mi) << 32) | ((u32)i << 8) | ci;
  int cnt = 0, ccnt = 0;
#pragma unroll 8
  for (int p = 0; p < SLICE; ++p) {
    u64 kj = kt[p];  // wave-uniform address -> LDS broadcast, no conflicts
    bool less = kj < ki;
    bool ceq = (((u32)(kj ^ ki)) & 0xffu) == 0u;
    cnt += less ? 1 : 0;
    ccnt += (less && ceq) ? 1 : 0;
  }
  rankp[slice * NBOX + i] = cnt;
  rcp[slice * NBOX + i] = ccnt;
}

// ---- K2: scatter by rank: sorted keys, offset boxes, order output, and
// per-class sorted lists (packed (idx<<16)|sorted_pos). All-in-one prep.
__global__ __launch_bounds__(256) void scatter_prep_kernel(
    const float* __restrict__ scores, const int* __restrict__ class_ids,
    const float4* __restrict__ boxes, const u32* __restrict__ gmax,
    const int* __restrict__ rankp, const int* __restrict__ rcp,
    u64* __restrict__ keys, float4* __restrict__ bnms,
    u32* __restrict__ clist, int* __restrict__ ccount,
    float* __restrict__ order_out, int* __restrict__ flag) {
  int i = blockIdx.x * 256 + threadIdx.x;
  int r = 0, rc = 0;
#pragma unroll
  for (int s = 0; s < NS; ++s) {  // coalesced within each slice row
    r += rankp[s * NBOX + i];
    rc += rcp[s * NBOX + i];
  }
  u32 mi = f32_mono(scores[i]);
  keys[r] = ((u64)(~mi) << 32) | (u32)i;  // clean key for fallback scan
  int cls = class_ids[i];
  float maxc = mono_f32(*gmax);
  float off = (float)cls * (maxc + 1.0f);
  float4 b = boxes[i];
  b.x += off; b.y += off; b.z += off; b.w += off;
  bnms[r] = b;
  order_out[r] = (float)i;
  if (rc < MAXC)
    clist[cls * MAXC + rc] = ((u32)i << 16) | (u32)r;
  else
    atomicOr(flag, 1);  // class overflow -> exact fallback
  atomicAdd(&ccount[cls], 1);
}

// ---- K3: per-class greedy NMS, all-register (blocks 0..79), + cross-class
// hazard check (block 80). Valid when flag stays 0; else fallback overwrites.
// Fast path: wave 0 only. Lane t holds boxes j = t, t+64, t+128, t+192 in
// registers; remv lives as 4 wave-uniform u64 (SGPR). Per kept row i:
// 4 readlanes broadcast box i, <=4 IoU+ballot passes OR into remv. No LDS.
__global__ __launch_bounds__(256) void class_nms_kernel(
    const u32* __restrict__ clist, const int* __restrict__ ccount,
    const float4* __restrict__ bnms, float* __restrict__ keep_out,
    const float4* __restrict__ boxes, const int* __restrict__ class_ids,
    const u32* __restrict__ gmax, int* __restrict__ flag, int n) {
  int t = threadIdx.x;

  if (blockIdx.x == NCLASS) {
    // Cross-class hazard check: adjacent-class offset boxes can only overlap
    // if one box hugs the top-right margin (x2,y2 > M-65; x1,y1 >= -64 by
    // construction) and the other the bottom-left margin (x1,y1 < 1).
    // Conservative IoU > 0.4 vs reference 0.5.
    __shared__ float4 bxA[CHKCAP], bxB[CHKCAP];
    __shared__ int clsA[CHKCAP], clsB[CHKCAP];
    __shared__ int na, nb;
    if (t == 0) { na = 0; nb = 0; }
    __syncthreads();
    float M = mono_f32(*gmax);
    float thrA = M - 65.0f;
    for (int base = 0; base < n; base += 256) {
      int i = base + t;
      float4 b = boxes[i];
      int cls = class_ids[i];
      if (b.z > thrA && b.w > thrA) {
        int p = atomicAdd(&na, 1);
        if (p < CHKCAP) { bxA[p] = b; clsA[p] = cls; }
      }
      if (b.x < 1.0f && b.y < 1.0f) {
        int p = atomicAdd(&nb, 1);
        if (p < CHKCAP) { bxB[p] = b; clsB[p] = cls; }
      }
    }
    __syncthreads();
    int NA = na < CHKCAP ? na : CHKCAP;
    int NB = nb < CHKCAP ? nb : CHKCAP;
    if (t == 0 && (na > CHKCAP || nb > CHKCAP)) atomicOr(flag, 1);
    bool hit = false;
    for (int pr = t; pr < NA * NB; pr += 256) {
      int a = pr / NB, b2 = pr % NB;
      if (clsB[b2] != clsA[a] + 1) continue;
      float offa = (float)clsA[a] * (M + 1.0f);
      float offb = (float)clsB[b2] * (M + 1.0f);
      float4 A = bxA[a], B = bxB[b2];
      A.x += offa; A.y += offa; A.z += offa; A.w += offa;
      B.x += offb; B.y += offb; B.z += offb; B.w += offb;
      float ltx = fmaxf(A.x, B.x), lty = fmaxf(A.y, B.y);
      float rbx = fminf(A.z, B.z), rby = fminf(A.w, B.w);
      float ww = fmaxf(rbx - ltx, 0.f), hh = fmaxf(rby - lty, 0.f);
      float inter = ww * hh;
      float aa = (A.z - A.x) * (A.w - A.y);
      float ab = (B.z - B.x) * (B.w - B.y);
      float iou = inter / (aa + ab - inter);
      if (iou > 0.4f) hit = true;
    }
    if (hit) atomicOr(flag, 1);
    return;
  }

  if (t >= 64) return;  // fast path: wave 0 only
  int c = blockIdx.x;
  int nc = ccount[c];
  if (nc > NCMAX) {  // ~9 sigma; exact fallback handles it
    if (t == 0) atomicOr(flag, 1);
    return;
  }

  u32 L[4];
  float4 B[4];
#pragma unroll
  for (int d = 0; d < 4; ++d) {
    int j = d * 64 + t;
    L[d] = (j < nc) ? clist[c * MAXC + j] : 0u;
    B[d] = bnms[L[d] & 0xffffu];  // j>=nc -> harmless read of bnms[0]
  }
  u64 r0 = 0, r1 = 0, r2 = 0, r3 = 0;  // wave-uniform remv (SGPR)

#define CHUNK(CC, RC, PASSES)                                                  \
  {                                                                            \
    int lim = nc - CC * 64;                                                    \
    if (lim > 0) {                                                             \
      if (lim > 64) lim = 64;                                                  \
      for (int ii = 0; ii < lim; ++ii) {                                       \
        if (!((RC >> ii) & 1ull)) {                                            \
          float bix = readlane_f(B[CC].x, ii);                                 \
          float biy = readlane_f(B[CC].y, ii);                                 \
          float biz = readlane_f(B[CC].z, ii);                                 \
          float biw = readlane_f(B[CC].w, ii);                                 \
          float area_i = (biz - bix) * (biw - biy);                            \
          PASSES                                                               \
        }                                                                      \
      }                                                                        \
    }                                                                          \
  }
#define PASS(DD, RD, JGUARD)                                                   \
  {                                                                            \
    float4 bj = B[DD];                                                         \
    float ltx = fmaxf(bix, bj.x), lty = fmaxf(biy, bj.y);                      \
    float rbx = fminf(biz, bj.z), rby = fminf(biw, bj.w);                      \
    float ww = fmaxf(rbx - ltx, 0.f), hh = fmaxf(rby - lty, 0.f);              \
    float inter = ww * hh;                                                     \
    float area_j = (bj.z - bj.x) * (bj.w - bj.y);                              \
    float iou = inter / (area_i + area_j - inter);                             \
    int j = DD * 64 + t;                                                       \
    bool p = (iou > 0.5f) && (j < nc) && (JGUARD);                             \
    RD |= __ballot(p);                                                         \
  }

  CHUNK(0, r0, PASS(0, r0, t > ii) PASS(1, r1, true) PASS(2, r2, true) PASS(3, r3, true))
  CHUNK(1, r1, PASS(1, r1, t > ii) PASS(2, r2, true) PASS(3, r3, true))
  CHUNK(2, r2, PASS(2, r2, t > ii) PASS(3, r3, true))
  CHUNK(3, r3, PASS(3, r3, t > ii))
#undef PASS
#undef CHUNK

  u64 rr[4] = {r0, r1, r2, r3};
#pragma unroll
  for (int d = 0; d < 4; ++d) {
    int j = d * 64 + t;
    if (j < nc) keep_out[L[d] >> 16] = ((rr[d] >> t) & 1ull) ? 0.0f : 1.0f;
  }
}

// ---- Exact fallback path (runs only when flag != 0) ----
__global__ __launch_bounds__(256) void mask_kernel(const float4* __restrict__ bnms,
                                                   u64* __restrict__ mask,
                                                   const int* __restrict__ flag, int n) {
  if (*flag == 0) return;
  int lane = threadIdx.x & 63;
  int wid = threadIdx.x >> 6;
  for (int rr = 0; rr < 8; ++rr) {
    int i = blockIdx.x * 8 + rr;
    float4 bi = bnms[i];
    float area_i = (bi.z - bi.x) * (bi.w - bi.y);
    for (int w = wid; w < NW64; w += 4) {
      int j = w * 64 + lane;
      float4 bj = bnms[j];
      float ltx = fmaxf(bi.x, bj.x), lty = fmaxf(bi.y, bj.y);
      float rbx = fminf(bi.z, bj.z), rby = fminf(bi.w, bj.w);
      float ww = fmaxf(rbx - ltx, 0.f), hh = fmaxf(rby - lty, 0.f);
      float inter = ww * hh;
      float area_j = (bj.z - bj.x) * (bj.w - bj.y);
      float iou = inter / (area_i + area_j - inter);
      u64 m = __ballot((iou > 0.5f) && (j > i));
      if (lane == 0) mask[(size_t)i * NW64 + w] = m;
    }
  }
}

__global__ __launch_bounds__(64) void scan_kernel(const u64* __restrict__ mask,
                                                  const u64* __restrict__ keys,
                                                  float* __restrict__ keep_out,
                                                  const int* __restrict__ flag) {
  if (*flag == 0) return;
  const int lane = threadIdx.x;
  u64 r0 = 0, r1 = 0;
  u64 X[32], Y[32];
#pragma unroll
  for (int r = 0; r < 16; ++r) {
    ulonglong2 v = *reinterpret_cast<const ulonglong2*>(mask + (size_t)r * NW64 + 2 * lane);
    X[2 * r] = v.x; X[2 * r + 1] = v.y;
  }
  u64 dg_cur = mask[(size_t)lane * NW64 + 0];
  u64 key_cur = keys[lane];
  u64 dg_nxt = 0, key_nxt = 0;

#define FILL(BUF, FBASE)                                                              \
  if ((FBASE) < NBOX) {                                                               \
    _Pragma("unroll")                                                                 \
    for (int r = 0; r < 16; ++r) {                                                    \
      ulonglong2 v = *reinterpret_cast<const ulonglong2*>(                            \
          mask + (size_t)((FBASE) + r) * NW64 + 2 * lane);                            \
      BUF[2 * r] = v.x; BUF[2 * r + 1] = v.y;                                         \
    }                                                                                 \
  }
#define STEP(BUFC, BUFN, S)                                                           \
  {                                                                                   \
    FILL(BUFN, b * 64 + ((S) + 1) * 16)                                               \
    _Pragma("unroll")                                                                 \
    for (int e = 0; e < 16; ++e) {                                                    \
      const int rl = (S) * 16 + e;                                                    \
      u64 d = readlane64(dg_cur, rl);                                                 \
      u64 bit = (w >> rl) & 1ull;                                                     \
      u64 sm = bit - 1ull;                                                            \
      w |= d & sm;                                                                    \
      K |= sm & (1ull << rl);                                                         \
      r0 |= BUFC[2 * e] & sm;                                                         \
      r1 |= BUFC[2 * e + 1] & sm;                                                     \
    }                                                                                 \
  }
  for (int b = 0; b < 128; ++b) {
    if (b + 1 < 128) {
      dg_nxt = mask[(size_t)((b + 1) * 64 + lane) * NW64 + (b + 1)];
      key_nxt = keys[(size_t)(b + 1) * 64 + lane];
    }
    u64 w = (b & 1) ? readlane64(r1, b >> 1) : readlane64(r0, b >> 1);
    u64 K = 0;
    STEP(X, Y, 0)
    STEP(Y, X, 1)
    STEP(X, Y, 2)
    STEP(Y, X, 3)
    u64 kb = (K >> lane) & 1ull;
    keep_out[(u32)key_cur] = kb ? 1.0f : 0.0f;
    dg_cur = dg_nxt;
    key_cur = key_nxt;
  }
#undef STEP
#undef FILL
}

extern "C" void kernel_launch(void* const* d_in, const int* in_sizes, int n_in,
                              void* d_out, int out_size, void* d_ws, size_t ws_size,
                              hipStream_t stream) {
  const float* deltas = (const float*)d_in[0];
  const float* locs = (const float*)d_in[1];
  const float* scores = (const float*)d_in[2];
  const int* class_ids = (const int*)d_in[3];
  const int* stride_p = (const int*)d_in[4];
  int n = in_sizes[2];  // 8192

  float* boxes_out = (float*)d_out;                  // n*4 floats
  float* keep_out = (float*)d_out + (size_t)n * 4;   // n floats (0/1)
  float* order_out = (float*)d_out + (size_t)n * 5;  // n floats (indices)

  // workspace layout
  u32* gmax = (u32*)d_ws;                        // @0
  int* flag = (int*)((char*)d_ws + 4);           // @4
  int* ccount = (int*)((char*)d_ws + 64);        // 80*4 B
  u64* keys = (u64*)((char*)d_ws + 4096);        // 64 KiB
  float4* bnms = (float4*)((char*)d_ws + 4096 + 65536);  // 128 KiB
  char* base2 = (char*)d_ws + 4096 + 65536 + 131072;
  int* rankp = (int*)base2;                       // NS*8192*4 = 512 KiB
  int* rcp = (int*)(base2 + 512 * 1024);          // 512 KiB
  u32* clist = (u32*)(base2 + 1024 * 1024);       // 80*512*4 = 160 KiB
  u64* mask = (u64*)base2;  // 8 MiB fallback overlay (lifetimes disjoint)

  hipMemsetAsync(d_ws, 0, 1024, stream);  // gmax + flag + ccount

  rank_decode_kernel<<<dim3(n / 256, NS), 256, 0, stream>>>(
      scores, class_ids, (const float4*)deltas, (const float2*)locs, stride_p,
      (float4*)boxes_out, gmax, rankp, rcp);

  scatter_prep_kernel<<<n / 256, 256, 0, stream>>>(
      scores, class_ids, (const float4*)boxes_out, gmax, rankp, rcp, keys,
      bnms, clist, ccount, order_out, flag);

  class_nms_kernel<<<NCLASS + 1, 256, 0, stream>>>(
      clist, ccount, bnms, keep_out, (const float4*)boxes_out, class_ids,
      gmax, flag, n);

  mask_kernel<<<n / 8, 256, 0, stream>>>(bnms, mask, flag, n);

  scan_kernel<<<1, 64, 0, stream>>>(mask, keys, keep_out, flag);
}

// Round 6
// 68.268 us; speedup vs baseline: 19.1623x; 1.0550x over previous
//
#include <hip/hip_runtime.h>

typedef unsigned long long u64;
typedef unsigned int u32;

#define NBOX 8192
#define NW64 128    // u64 words per mask row (fallback path)
#define NCLASS 80
#define MAXC 512    // clist capacity per class
#define NCMAX 256   // fast-path class size cap (nc>256 is ~9 sigma -> fallback)
#define CHKCAP 256
#define NS 16       // rank slices
#define SLICE (NBOX / NS)  // 512
#define NBLK (NBOX / 256)  // 32 rank blocks per slice

// ---- monotone float<->uint mapping (order-preserving for all floats) ----
__device__ __forceinline__ u32 f32_mono(float f) {
  u32 u = __float_as_uint(f);
  return (u & 0x80000000u) ? ~u : (u | 0x80000000u);
}
__device__ __forceinline__ float mono_f32(u32 u) {
  u32 b = (u & 0x80000000u) ? (u ^ 0x80000000u) : ~u;
  return __uint_as_float(b);
}
__device__ __forceinline__ float readlane_f(float v, int l) {
  return __uint_as_float(__builtin_amdgcn_readlane(__float_as_uint(v), l));
}
// reduce 32-entry u32 array of block maxima, in-register (reads are L2-hot)
__device__ __forceinline__ u32 reduce_bmax(const u32* __restrict__ bmax, int t) {
  u32 bm = bmax[t & 31];
#pragma unroll
  for (int off = 16; off > 0; off >>= 1) {
    u32 o = __shfl_xor(bm, off);
    bm = (bm > o) ? bm : o;
  }
  return bm;  // uniform within each 32-lane group
}

// ---- K1: fused rank-by-enumeration + box decode/block-max (slice 0) + init.
// Rank key: (~mono(score) << 32) | (idx << 8) | cls.
__global__ __launch_bounds__(256) void rank_decode_kernel(
    const float* __restrict__ scores, const int* __restrict__ class_ids,
    const float4* __restrict__ deltas, const float2* __restrict__ locs,
    const int* __restrict__ stride_p, float4* __restrict__ boxes_out,
    u32* __restrict__ bmax, int* __restrict__ flag, int* __restrict__ ccount,
    int* __restrict__ rankp, int* __restrict__ rcp) {
  int t = threadIdx.x;
  int i = blockIdx.x * 256 + t;
  int slice = blockIdx.y;

  __shared__ u64 kt[SLICE];
  __shared__ u32 wmax[4];

  if (slice == 0) {  // decode boxes + block max + ws init (block-uniform branch)
    float s = (float)(*stride_p);
    float4 d = deltas[i];
    d.x = fmaxf(d.x, 0.f); d.y = fmaxf(d.y, 0.f);
    d.z = fmaxf(d.z, 0.f); d.w = fmaxf(d.w, 0.f);
    float2 c = locs[i];
    float4 b;
    b.x = c.x - s * d.x;
    b.y = c.y - s * d.y;
    b.z = c.x + s * d.z;
    b.w = c.y + s * d.w;
    boxes_out[i] = b;
    float m = fmaxf(fmaxf(b.x, b.y), fmaxf(b.z, b.w));
    u32 u = f32_mono(m);
#pragma unroll
    for (int off = 32; off > 0; off >>= 1) {
      u32 o = __shfl_xor(u, off);
      u = (u > o) ? u : o;
    }
    if ((t & 63) == 0) wmax[t >> 6] = u;
    __syncthreads();
    if (t == 0) {
      u32 m0 = wmax[0] > wmax[1] ? wmax[0] : wmax[1];
      u32 m1 = wmax[2] > wmax[3] ? wmax[2] : wmax[3];
      bmax[blockIdx.x] = m0 > m1 ? m0 : m1;  // plain store, no init needed
    }
    if (blockIdx.x == 0) {  // init flag/ccount before any writer (stream order)
      if (t == 0) *flag = 0;
      if (t < NCLASS) ccount[t] = 0;
    }
  }

  for (int p = t; p < SLICE; p += 256) {
    int j = slice * SLICE + p;
    u32 mj = f32_mono(scores[j]);
    kt[p] = ((u64)(~mj) << 32) | ((u32)j << 8) | (u32)(class_ids[j] & 0xff);
  }
  __syncthreads();

  u32 mi = f32_mono(scores[i]);
  u32 ci = (u32)(class_ids[i] & 0xff);
  u64 ki = ((u64)(~mi) << 32) | ((u32)i << 8) | ci;
  int cnt = 0, ccnt = 0;
#pragma unroll 8
  for (int p = 0; p < SLICE; ++p) {
    u64 kj = kt[p];  // wave-uniform address -> LDS broadcast, no conflicts
    bool less = kj < ki;
    bool ceq = (((u32)(kj ^ ki)) & 0xffu) == 0u;
    cnt += less ? 1 : 0;
    ccnt += (less && ceq) ? 1 : 0;
  }
  rankp[slice * NBOX + i] = cnt;
  rcp[slice * NBOX + i] = ccnt;
}

// ---- K2: scatter by rank: sorted keys, offset boxes, order output, and
// per-class sorted lists (packed (idx<<16)|sorted_pos). All-in-one prep.
__global__ __launch_bounds__(256) void scatter_prep_kernel(
    const float* __restrict__ scores, const int* __restrict__ class_ids,
    const float4* __restrict__ boxes, const u32* __restrict__ bmax,
    const int* __restrict__ rankp, const int* __restrict__ rcp,
    u64* __restrict__ keys, float4* __restrict__ bnms,
    u32* __restrict__ clist, int* __restrict__ ccount,
    float* __restrict__ order_out, int* __restrict__ flag) {
  int t = threadIdx.x;
  int i = blockIdx.x * 256 + t;
  int r = 0, rc = 0;
#pragma unroll
  for (int s = 0; s < NS; ++s) {  // coalesced within each slice row
    r += rankp[s * NBOX + i];
    rc += rcp[s * NBOX + i];
  }
  float maxc = mono_f32(reduce_bmax(bmax, t));
  u32 mi = f32_mono(scores[i]);
  keys[r] = ((u64)(~mi) << 32) | (u32)i;  // clean key for fallback scan
  int cls = class_ids[i];
  float off = (float)cls * (maxc + 1.0f);
  float4 b = boxes[i];
  b.x += off; b.y += off; b.z += off; b.w += off;
  bnms[r] = b;
  order_out[r] = (float)i;
  if (rc < MAXC)
    clist[cls * MAXC + rc] = ((u32)i << 16) | (u32)r;
  else
    atomicOr(flag, 1);  // class overflow -> exact fallback
  atomicAdd(&ccount[cls], 1);
}

// ---- K3: per-class greedy NMS, all-register (blocks 0..79), + cross-class
// hazard check (block 80). Valid when flag stays 0; else fallback overwrites.
// Fast path: wave 0 only. Lane t holds boxes j = t, t+64, t+128, t+192 in
// registers; remv lives as 4 wave-uniform u64 (SGPR). Per kept row i:
// 4 readlanes broadcast box i, <=4 IoU+ballot passes OR into remv. No LDS.
__global__ __launch_bounds__(256) void class_nms_kernel(
    const u32* __restrict__ clist, const int* __restrict__ ccount,
    const float4* __restrict__ bnms, float* __restrict__ keep_out,
    const float4* __restrict__ boxes, const int* __restrict__ class_ids,
    const u32* __restrict__ bmax, int* __restrict__ flag, int n) {
  int t = threadIdx.x;

  if (blockIdx.x == NCLASS) {
    // Cross-class hazard check: adjacent-class offset boxes can only overlap
    // if one box hugs the top-right margin (x2,y2 > M-65; x1,y1 >= -64 by
    // construction) and the other the bottom-left margin (x1,y1 < 1).
    // Conservative IoU > 0.4 vs reference 0.5.
    __shared__ float4 bxA[CHKCAP], bxB[CHKCAP];
    __shared__ int clsA[CHKCAP], clsB[CHKCAP];
    __shared__ int na, nb;
    if (t == 0) { na = 0; nb = 0; }
    __syncthreads();
    float M = mono_f32(reduce_bmax(bmax, t));
    float thrA = M - 65.0f;
    for (int base = 0; base < n; base += 256) {
      int i = base + t;
      float4 b = boxes[i];
      int cls = class_ids[i];
      if (b.z > thrA && b.w > thrA) {
        int p = atomicAdd(&na, 1);
        if (p < CHKCAP) { bxA[p] = b; clsA[p] = cls; }
      }
      if (b.x < 1.0f && b.y < 1.0f) {
        int p = atomicAdd(&nb, 1);
        if (p < CHKCAP) { bxB[p] = b; clsB[p] = cls; }
      }
    }
    __syncthreads();
    int NA = na < CHKCAP ? na : CHKCAP;
    int NB = nb < CHKCAP ? nb : CHKCAP;
    if (t == 0 && (na > CHKCAP || nb > CHKCAP)) atomicOr(flag, 1);
    bool hit = false;
    for (int pr = t; pr < NA * NB; pr += 256) {
      int a = pr / NB, b2 = pr % NB;
      if (clsB[b2] != clsA[a] + 1) continue;
      float offa = (float)clsA[a] * (M + 1.0f);
      float offb = (float)clsB[b2] * (M + 1.0f);
      float4 A = bxA[a], B = bxB[b2];
      A.x += offa; A.y += offa; A.z += offa; A.w += offa;
      B.x += offb; B.y += offb; B.z += offb; B.w += offb;
      float ltx = fmaxf(A.x, B.x), lty = fmaxf(A.y, B.y);
      float rbx = fminf(A.z, B.z), rby = fminf(A.w, B.w);
      float ww = fmaxf(rbx - ltx, 0.f), hh = fmaxf(rby - lty, 0.f);
      float inter = ww * hh;
      float aa = (A.z - A.x) * (A.w - A.y);
      float ab = (B.z - B.x) * (B.w - B.y);
      float iou = inter / (aa + ab - inter);
      if (iou > 0.4f) hit = true;
    }
    if (hit) atomicOr(flag, 1);
    return;
  }

  if (t >= 64) return;  // fast path: wave 0 only
  int c = blockIdx.x;
  int nc = ccount[c];
  if (nc > NCMAX) {  // ~9 sigma; exact fallback handles it
    if (t == 0) atomicOr(flag, 1);
    return;
  }

  u32 L[4];
  float4 B[4];
#pragma unroll
  for (int d = 0; d < 4; ++d) {
    int j = d * 64 + t;
    L[d] = (j < nc) ? clist[c * MAXC + j] : 0u;
    B[d] = bnms[L[d] & 0xffffu];  // j>=nc -> harmless read of bnms[0]
  }
  u64 r0 = 0, r1 = 0, r2 = 0, r3 = 0;  // wave-uniform remv (SGPR)

#define CHUNK(CC, RC, PASSES)                                                  \
  {                                                                            \
    int lim = nc - CC * 64;                                                    \
    if (lim > 0) {                                                             \
      if (lim > 64) lim = 64;                                                  \
      for (int ii = 0; ii < lim; ++ii) {                                       \
        if (!((RC >> ii) & 1ull)) {                                            \
          float bix = readlane_f(B[CC].x, ii);                                 \
          float biy = readlane_f(B[CC].y, ii);                                 \
          float biz = readlane_f(B[CC].z, ii);                                 \
          float biw = readlane_f(B[CC].w, ii);                                 \
          float area_i = (biz - bix) * (biw - biy);                            \
          PASSES                                                               \
        }                                                                      \
      }                                                                        \
    }                                                                          \
  }
#define PASS(DD, RD, JGUARD)                                                   \
  {                                                                            \
    float4 bj = B[DD];                                                         \
    float ltx = fmaxf(bix, bj.x), lty = fmaxf(biy, bj.y);                      \
    float rbx = fminf(biz, bj.z), rby = fminf(biw, bj.w);                      \
    float ww = fmaxf(rbx - ltx, 0.f), hh = fmaxf(rby - lty, 0.f);              \
    float inter = ww * hh;                                                     \
    float area_j = (bj.z - bj.x) * (bj.w - bj.y);                              \
    float iou = inter / (area_i + area_j - inter);                             \
    int j = DD * 64 + t;                                                       \
    bool p = (iou > 0.5f) && (j < nc) && (JGUARD);                             \
    RD |= __ballot(p);                                                         \
  }

  CHUNK(0, r0, PASS(0, r0, t > ii) PASS(1, r1, true) PASS(2, r2, true) PASS(3, r3, true))
  CHUNK(1, r1, PASS(1, r1, t > ii) PASS(2, r2, true) PASS(3, r3, true))
  CHUNK(2, r2, PASS(2, r2, t > ii) PASS(3, r3, true))
  CHUNK(3, r3, PASS(3, r3, t > ii))
#undef PASS
#undef CHUNK

  u64 rr[4] = {r0, r1, r2, r3};
#pragma unroll
  for (int d = 0; d < 4; ++d) {
    int j = d * 64 + t;
    if (j < nc) keep_out[L[d] >> 16] = ((rr[d] >> t) & 1ull) ? 0.0f : 1.0f;
  }
}

// ---- K4: exact single-block fallback (runs only when flag != 0; never on
// this data distribution — correctness insurance, not a perf path).
__global__ __launch_bounds__(256) void fallback_kernel(
    const float4* __restrict__ bnms, const u64* __restrict__ keys,
    float* __restrict__ keep_out, const int* __restrict__ flag, int n) {
  if (*flag == 0) return;
  __shared__ u64 remv[NW64];
  int t = threadIdx.x;
  for (int k = t; k < NW64; k += 256) remv[k] = 0;
  __syncthreads();
  if (t < 64) {  // wave 0: serial greedy over all n sorted boxes
    int lane = t;
    for (int i = 0; i < n; ++i) {
      if ((remv[i >> 6] >> (i & 63)) & 1ull) continue;
      float4 bi = bnms[i];
      float area_i = (bi.z - bi.x) * (bi.w - bi.y);
      for (int jb = i + 1; jb < n; jb += 64) {
        int j = jb + lane;
        bool p = false;
        if (j < n) {
          float4 bj = bnms[j];
          float ltx = fmaxf(bi.x, bj.x), lty = fmaxf(bi.y, bj.y);
          float rbx = fminf(bi.z, bj.z), rby = fminf(bi.w, bj.w);
          float ww = fmaxf(rbx - ltx, 0.f), hh = fmaxf(rby - lty, 0.f);
          float inter = ww * hh;
          float area_j = (bj.z - bj.x) * (bj.w - bj.y);
          float iou = inter / (area_i + area_j - inter);
          p = iou > 0.5f;
        }
        u64 m = __ballot(p);
        if (lane == 0 && m) {
          int w0 = jb >> 6, sh = jb & 63;
          remv[w0] |= (m << sh);
          if (sh && (w0 + 1) < NW64) remv[w0 + 1] |= (m >> (64 - sh));
        }
      }
    }
  }
  __syncthreads();
  for (int k = t; k < n; k += 256)
    keep_out[(u32)keys[k]] = ((remv[k >> 6] >> (k & 63)) & 1ull) ? 0.0f : 1.0f;
}

extern "C" void kernel_launch(void* const* d_in, const int* in_sizes, int n_in,
                              void* d_out, int out_size, void* d_ws, size_t ws_size,
                              hipStream_t stream) {
  const float* deltas = (const float*)d_in[0];
  const float* locs = (const float*)d_in[1];
  const float* scores = (const float*)d_in[2];
  const int* class_ids = (const int*)d_in[3];
  const int* stride_p = (const int*)d_in[4];
  int n = in_sizes[2];  // 8192

  float* boxes_out = (float*)d_out;                  // n*4 floats
  float* keep_out = (float*)d_out + (size_t)n * 4;   // n floats (0/1)
  float* order_out = (float*)d_out + (size_t)n * 5;  // n floats (indices)

  // workspace layout (no pre-zeroing required anywhere)
  u32* bmax = (u32*)d_ws;                        // 32*4 B (plain-stored)
  int* flag = (int*)((char*)d_ws + 256);         // init'd by rank_decode
  int* ccount = (int*)((char*)d_ws + 512);       // 80*4 B, init'd by rank_decode
  u64* keys = (u64*)((char*)d_ws + 4096);        // 64 KiB
  float4* bnms = (float4*)((char*)d_ws + 4096 + 65536);  // 128 KiB
  char* base2 = (char*)d_ws + 4096 + 65536 + 131072;
  int* rankp = (int*)base2;                       // NS*8192*4 = 512 KiB
  int* rcp = (int*)(base2 + 512 * 1024);          // 512 KiB
  u32* clist = (u32*)(base2 + 1024 * 1024);       // 80*512*4 = 160 KiB

  rank_decode_kernel<<<dim3(NBLK, NS), 256, 0, stream>>>(
      scores, class_ids, (const float4*)deltas, (const float2*)locs, stride_p,
      (float4*)boxes_out, bmax, flag, ccount, rankp, rcp);

  scatter_prep_kernel<<<n / 256, 256, 0, stream>>>(
      scores, class_ids, (const float4*)boxes_out, bmax, rankp, rcp, keys,
      bnms, clist, ccount, order_out, flag);

  class_nms_kernel<<<NCLASS + 1, 256, 0, stream>>>(
      clist, ccount, bnms, keep_out, (const float4*)boxes_out, class_ids,
      bmax, flag, n);

  fallback_kernel<<<1, 256, 0, stream>>>(bnms, keys, keep_out, flag, n);
}